// Round 2
// baseline (228.097 us; speedup 1.0000x reference)
//
#include <hip/hip_runtime.h>
#include <stdint.h>

typedef unsigned int u32;
typedef unsigned long long u64;

#define E_CNT   8192
#define N_CNT   4096
#define TOT_N   (1u << 26)     // E*E elements, one threefry eval each (partitionable)
#define OUT_K   16384          // K*E = 2*8192
#define NODE_BM_WORDS 128      // 4096 bits / 32
#define N_CHUNKS 1024          // 2^26 bits / 2^16 bits-per-chunk

// ---- workspace layout (bytes); total = 0x210000 + 8 MiB ~= 10.06 MB ----
#define OFF_BAD      0x000000  // u32[4096*128]   2 MiB  bad-bitmap per node
#define OFF_CNT_DST  0x200000  // u32[4096]
#define OFF_CNT_SRC  0x204000  // u32[4096]
#define OFF_CCOUNT   0x208000  // u32[1024] chunk keep-counts
#define OFF_COFF     0x209000  // u32[1024] chunk exclusive offsets
#define OFF_SCALARS  0x20A000  // [0]=num_neg u32, [1]=keep_prob f32
#define OFF_KEEPBM   0x210000  // u64[1<<20]     8 MiB  keep bitmap
#define ZERO_BYTES   0x20A100  // zero everything up through scalars

__device__ __forceinline__ u32 rotl32(u32 x, u32 d) { return (x << d) | (x >> (32u - d)); }

// JAX threefry2x32, key = (0, 42)  (jax.random.key(42) -> data [0,42])
__device__ __forceinline__ void threefry_0_42(u32 x0, u32 x1, u32& o0, u32& o1) {
  const u32 k0 = 0u, k1 = 42u, k2 = 0x1BD11BF0u; // 0 ^ 42 ^ 0x1BD11BDA
  x0 += k0; x1 += k1;
#define TF_R(r) { x0 += x1; x1 = rotl32(x1, r); x1 ^= x0; }
  TF_R(13) TF_R(15) TF_R(26) TF_R(6)
  x0 += k1; x1 += k2 + 1u;
  TF_R(17) TF_R(29) TF_R(16) TF_R(24)
  x0 += k2; x1 += k0 + 2u;
  TF_R(13) TF_R(15) TF_R(26) TF_R(6)
  x0 += k0; x1 += k1 + 3u;
  TF_R(17) TF_R(29) TF_R(16) TF_R(24)
  x0 += k1; x1 += k2 + 4u;
  TF_R(13) TF_R(15) TF_R(26) TF_R(6)
  x0 += k2; x1 += k0 + 5u;
#undef TF_R
  o0 = x0; o1 = x1;
}

// JAX uniform: bitcast((bits>>9)|0x3f800000) - 1.0f
__device__ __forceinline__ float bits_to_unif(u32 b) {
  return __uint_as_float((b >> 9) | 0x3f800000u) - 1.0f;
}

// --- K1: bad bitmap (self + out-neighbors) and dst/src histograms ---
__global__ void k_build(const int* __restrict__ src, const int* __restrict__ dst,
                        u32* __restrict__ bad, u32* __restrict__ cnt_dst,
                        u32* __restrict__ cnt_src) {
  int tid = blockIdx.x * 256 + threadIdx.x;
  if (tid < N_CNT) {
    atomicOr(&bad[(u32)tid * NODE_BM_WORDS + ((u32)tid >> 5)], 1u << (tid & 31));
  }
  if (tid < E_CNT) {
    u32 s = (u32)src[tid], d = (u32)dst[tid];
    atomicOr(&bad[s * NODE_BM_WORDS + (d >> 5)], 1u << (d & 31));
    atomicAdd(&cnt_dst[d], 1u);
    atomicAdd(&cnt_src[s], 1u);
  }
}

// --- K2: num_negatives = sum_n cnt_src[n] * (E - sum_{v in badset(n)} cnt_dst[v]) ---
__global__ void k_rowcount(const u32* __restrict__ bad, const u32* __restrict__ cnt_dst,
                           const u32* __restrict__ cnt_src, u32* __restrict__ num_neg) {
  int n = blockIdx.x * 256 + threadIdx.x;  // < 4096
  u32 sum = 0;
  const u32* row = bad + (u32)n * NODE_BM_WORDS;
  for (int w = 0; w < NODE_BM_WORDS; ++w) {
    u32 bits = row[w];
    while (bits) { int b = __ffs(bits) - 1; sum += cnt_dst[w * 32 + b]; bits &= bits - 1; }
  }
  u32 contrib = ((u32)E_CNT - sum) * cnt_src[n];
  __shared__ u32 red[256];
  red[threadIdx.x] = contrib; __syncthreads();
  for (int off = 128; off > 0; off >>= 1) {
    if (threadIdx.x < off) red[threadIdx.x] += red[threadIdx.x + off];
    __syncthreads();
  }
  if (threadIdx.x == 0) atomicAdd(num_neg, red[0]);
}

// --- K3: keep_prob = f32(2) / f32(num_neg // E) ---
__global__ void k_prob(const u32* __restrict__ num_neg, float* __restrict__ kp) {
  u32 ratio = num_neg[0] / (u32)E_CNT;
  kp[0] = 2.0f / (float)ratio;
}

// --- K4: partitionable threefry over all 2^26 elements -> keep bitmap + chunk counts
// bits[i] = o0 ^ o1 where (o0,o1) = threefry2x32(key, (hi32(i)=0, lo32(i)=i)) ---
__global__ void __launch_bounds__(256) k_sample(const int* __restrict__ src,
                                                const int* __restrict__ dst,
                                                const u32* __restrict__ bad,
                                                const float* __restrict__ kp_p,
                                                u64* __restrict__ keep_bm,
                                                u32* __restrict__ ccount) {
  u32 i = blockIdx.x * 256u + threadIdx.x;  // < 2^26
  u32 o0, o1;
  threefry_0_42(0u, i, o0, o1);
  float u = bits_to_unif(o0 ^ o1);
  float kp = kp_p[0];
  bool keep = u < kp;
  if (keep) {  // rare (~2.4e-4): check m = !bad_bit(src[row], dst[col])
    u32 n = (u32)src[i >> 13]; u32 v = (u32)dst[i & 8191];
    keep = ((bad[n * NODE_BM_WORDS + (v >> 5)] >> (v & 31)) & 1u) == 0u;
  }
  u64 m = __ballot(keep);
  if ((threadIdx.x & 63) == 0) {
    keep_bm[i >> 6] = m;   // lane0: i is the wave-base index
    if (m) atomicAdd(&ccount[i >> 16], (u32)__popcll(m));
  }
}

// --- K5: exclusive prefix over 1024 chunk counts ---
__global__ void k_scan(const u32* __restrict__ ccount, u32* __restrict__ coff) {
  __shared__ u32 s[N_CHUNKS];
  int t = threadIdx.x;
  u32 mine = ccount[t];
  s[t] = mine; __syncthreads();
  for (int off = 1; off < N_CHUNKS; off <<= 1) {
    u32 v = (t >= off) ? s[t - off] : 0u;
    __syncthreads();
    s[t] += v;
    __syncthreads();
  }
  coff[t] = s[t] - mine;  // exclusive
}

// --- K6: prefill padding value (fill_value=0 -> idx 0 -> (src[0], dst[0])) ---
__global__ void k_prefill(const int* __restrict__ src, const int* __restrict__ dst,
                          int* __restrict__ out) {
  int r = blockIdx.x * 256 + threadIdx.x;  // < 16384
  out[r] = src[0];
  out[OUT_K + r] = dst[0];
}

// --- K7: ordered compaction, first 16384 kept indices ---
__global__ void k_compact(const int* __restrict__ src, const int* __restrict__ dst,
                          const u64* __restrict__ keep_bm, const u32* __restrict__ coff,
                          int* __restrict__ out) {
  int c = blockIdx.x;                       // chunk id, 1024 u64 words each
  const u64* words = keep_bm + (size_t)c * 1024;
  int t = threadIdx.x;                      // 256 threads, 4 words each (in order)
  u64 w[4];
  u32 cnt = 0;
#pragma unroll
  for (int k = 0; k < 4; ++k) { w[k] = words[4 * t + k]; cnt += (u32)__popcll(w[k]); }
  __shared__ u32 s[256];
  s[t] = cnt; __syncthreads();
  for (int off = 1; off < 256; off <<= 1) {
    u32 v = (t >= off) ? s[t - off] : 0u;
    __syncthreads();
    s[t] += v;
    __syncthreads();
  }
  u32 rank = coff[c] + s[t] - cnt;          // global rank of my first set bit
  u32 tbase = (u32)c * 65536u + (u32)t * 256u;
#pragma unroll
  for (int k = 0; k < 4; ++k) {
    u64 bits = w[k];
    while (bits) {
      int b = __ffsll((unsigned long long)bits) - 1;
      if (rank < OUT_K) {
        u32 tt = tbase + (u32)k * 64u + (u32)b;
        out[rank]         = src[tt >> 13];   // edge_src[rows]
        out[OUT_K + rank] = dst[tt & 8191];  // edge_dst[cols]
      }
      rank++;
      bits &= bits - 1;
    }
  }
}

extern "C" void kernel_launch(void* const* d_in, const int* in_sizes, int n_in,
                              void* d_out, int out_size, void* d_ws, size_t ws_size,
                              hipStream_t stream) {
  const int* src = (const int*)d_in[1];  // edge_src
  const int* dst = (const int*)d_in[2];  // edge_dst  (node_feature d_in[0] unused)
  int* out = (int*)d_out;                // [edge_src_neg(16384) | edge_dst_neg(16384)]
  char* ws = (char*)d_ws;

  u32*   bad     = (u32*)(ws + OFF_BAD);
  u32*   cnt_dst = (u32*)(ws + OFF_CNT_DST);
  u32*   cnt_src = (u32*)(ws + OFF_CNT_SRC);
  u32*   ccount  = (u32*)(ws + OFF_CCOUNT);
  u32*   coff    = (u32*)(ws + OFF_COFF);
  u32*   num_neg = (u32*)(ws + OFF_SCALARS);
  float* kp      = (float*)(ws + OFF_SCALARS + 4);
  u64*   keep_bm = (u64*)(ws + OFF_KEEPBM);

  hipMemsetAsync(ws, 0, ZERO_BYTES, stream);
  k_build<<<(E_CNT + 255) / 256, 256, 0, stream>>>(src, dst, bad, cnt_dst, cnt_src);
  k_rowcount<<<N_CNT / 256, 256, 0, stream>>>(bad, cnt_dst, cnt_src, num_neg);
  k_prob<<<1, 1, 0, stream>>>(num_neg, kp);
  k_sample<<<TOT_N / 256, 256, 0, stream>>>(src, dst, bad, kp, keep_bm, ccount);
  k_scan<<<1, N_CHUNKS, 0, stream>>>(ccount, coff);
  k_prefill<<<OUT_K / 256, 256, 0, stream>>>(src, dst, out);
  k_compact<<<N_CHUNKS, 256, 0, stream>>>(src, dst, keep_bm, coff, out);
}